// Round 1
// baseline (356.579 us; speedup 1.0000x reference)
//
#include <hip/hip_runtime.h>
#include <math.h>

// Problem constants (from reference setup_inputs): img (16,8,512,512) fp32,
// params (16,3) fp32, output (16,8,512,512) fp32.
constexpr int B = 16, C = 8, H = 512, W = 512;
constexpr int HW = H * W;              // 2^18
constexpr int LOG_HW = 18, LOG_W = 9;

// One thread per (b,y,x); loops over C=8 channels so grid coords, bilinear
// weights, and the 4 gather offsets are computed once and reused 8x.
__global__ __launch_bounds__(256) void grid_sampler_kernel(
    const float* __restrict__ img,
    const float* __restrict__ params,
    float* __restrict__ out) {
    int idx = blockIdx.x * blockDim.x + threadIdx.x;   // over B*H*W
    int b   = idx >> LOG_HW;                           // wave-uniform
    int rem = idx & (HW - 1);
    int y   = rem >> LOG_W;
    int x   = rem & (W - 1);

    // Per-batch params: b is uniform across the wave -> scalar loads.
    float tx = params[b * 3 + 0] * (1.0f / W);
    float ty = params[b * 3 + 1] * (1.0f / H);
    float th = params[b * 3 + 2];
    float cs = cosf(th);
    float sn = sinf(th);

    // Normalized grid coords.
    float xs = (2.0f * (float)x + 1.0f) * (1.0f / W) - 1.0f;
    float ys = (2.0f * (float)y + 1.0f) * (1.0f / H) - 1.0f;
    float gx = cs * xs - sn * ys + tx;
    float gy = sn * xs + cs * ys + ty;

    // Source-space coords.
    float ix = ((gx + 1.0f) * (float)W - 1.0f) * 0.5f;
    float iy = ((gy + 1.0f) * (float)H - 1.0f) * 0.5f;
    float x0f = floorf(ix), y0f = floorf(iy);
    int x0 = (int)x0f, y0 = (int)y0f;
    int x1 = x0 + 1,  y1 = y0 + 1;
    float wx1 = ix - x0f, wx0 = 1.0f - wx1;
    float wy1 = iy - y0f, wy0 = 1.0f - wy1;

    // Zero-padding: fold validity into weights, clamp indices for the read.
    bool vx0 = (x0 >= 0) & (x0 < W);
    bool vx1 = (x1 >= 0) & (x1 < W);
    bool vy0 = (y0 >= 0) & (y0 < H);
    bool vy1 = (y1 >= 0) & (y1 < H);
    float w00 = wy0 * wx0 * ((vy0 & vx0) ? 1.0f : 0.0f);
    float w01 = wy0 * wx1 * ((vy0 & vx1) ? 1.0f : 0.0f);
    float w10 = wy1 * wx0 * ((vy1 & vx0) ? 1.0f : 0.0f);
    float w11 = wy1 * wx1 * ((vy1 & vx1) ? 1.0f : 0.0f);

    int x0c = min(max(x0, 0), W - 1), x1c = min(max(x1, 0), W - 1);
    int y0c = min(max(y0, 0), H - 1), y1c = min(max(y1, 0), H - 1);
    int o00 = (y0c << LOG_W) + x0c;
    int o01 = (y0c << LOG_W) + x1c;
    int o10 = (y1c << LOG_W) + x0c;
    int o11 = (y1c << LOG_W) + x1c;

    const float* ibase = img + (size_t)b * C * HW;
    float*       obase = out + (size_t)b * C * HW + rem;
#pragma unroll
    for (int ch = 0; ch < C; ++ch) {
        const float* p = ibase + ch * HW;
        float v = p[o00] * w00 + p[o01] * w01 + p[o10] * w10 + p[o11] * w11;
        obase[ch * HW] = v;
    }
}

extern "C" void kernel_launch(void* const* d_in, const int* in_sizes, int n_in,
                              void* d_out, int out_size, void* d_ws, size_t ws_size,
                              hipStream_t stream) {
    const float* img    = (const float*)d_in[0];
    const float* params = (const float*)d_in[1];
    float*       out    = (float*)d_out;

    constexpr int total = B * H * W;            // 4,194,304 threads
    constexpr int block = 256;
    constexpr int grid  = total / block;        // exact
    grid_sampler_kernel<<<grid, block, 0, stream>>>(img, params, out);
}

// Round 2
// 266.077 us; speedup vs baseline: 1.3401x; 1.3401x over previous
//
#include <hip/hip_runtime.h>
#include <math.h>

// img (16,8,512,512) fp32, params (16,3) fp32, out (16,8,512,512) fp32.
constexpr int B = 16, C = 8, H = 512, W = 512;
constexpr int HW = H * W;
constexpr int TILE = 32;           // 32x32 output tile per block
// Source bbox of a rotated 32x32 tile: span <= 31*(|c|+|s|)+3 <= 46.85 -> 46,
// +2 safety. Stride forced odd (<=49). Max LDS index < 48*49+48 < 2400.
constexpr int LDS_FLOATS = 2400;

__global__ __launch_bounds__(256) void grid_sampler_kernel(
    const float* __restrict__ img,
    const float* __restrict__ params,
    float* __restrict__ out) {
    __shared__ float lds[LDS_FLOATS];
    const int tid = threadIdx.x;
    const int blk = blockIdx.x;
    const int b   = blk >> 8;            // 256 tiles (16x16) per batch
    const int tt  = blk & 255;
    const int ty0 = (tt >> 4) * TILE;
    const int tx0 = (tt & 15) * TILE;

    // Wave-uniform per-batch params.
    const float tpx = params[b * 3 + 0] * (1.0f / W);
    const float tpy = params[b * 3 + 1] * (1.0f / H);
    const float th  = params[b * 3 + 2];
    const float c = cosf(th), s = sinf(th);

    // Same expression sequence for bbox corners and per-pixel sampling:
    // fp rounding is monotone here, so per-pixel ix/iy stay inside the
    // corner-derived bbox.
    auto srcxy = [&](float x, float y, float& ix, float& iy) {
        float xs = (2.0f * x + 1.0f) * (1.0f / W) - 1.0f;
        float ys = (2.0f * y + 1.0f) * (1.0f / H) - 1.0f;
        float gx = c * xs - s * ys + tpx;
        float gy = s * xs + c * ys + tpy;
        ix = ((gx + 1.0f) * (float)W - 1.0f) * 0.5f;
        iy = ((gy + 1.0f) * (float)H - 1.0f) * 0.5f;
    };

    float ixa, iya, ixb, iyb, ixc, iyc, ixd, iyd;
    srcxy((float)tx0,            (float)ty0,            ixa, iya);
    srcxy((float)(tx0 + TILE-1), (float)ty0,            ixb, iyb);
    srcxy((float)tx0,            (float)(ty0 + TILE-1), ixc, iyc);
    srcxy((float)(tx0 + TILE-1), (float)(ty0 + TILE-1), ixd, iyd);
    const float ixmin = fminf(fminf(ixa, ixb), fminf(ixc, ixd));
    const float ixmax = fmaxf(fmaxf(ixa, ixb), fmaxf(ixc, ixd));
    const float iymin = fminf(fminf(iya, iyb), fminf(iyc, iyd));
    const float iymax = fmaxf(fmaxf(iya, iyb), fmaxf(iyc, iyd));
    const int xlo = min(max((int)floorf(ixmin), 0), W - 1);
    const int xhi = min(max((int)floorf(ixmax) + 1, 0), W - 1);
    const int ylo = min(max((int)floorf(iymin), 0), H - 1);
    const int yhi = min(max((int)floorf(iymax) + 1, 0), H - 1);
    const int bw = xhi - xlo + 1;        // <= 48, >= 1
    const int bh = yhi - ylo + 1;
    const int stride = bw | 1;           // odd stride -> benign LDS banking

    // Per-thread outputs: ox fixed, 4 rows spaced by 8. Compute grid math,
    // folded weights, and LDS offsets ONCE; reuse across all 8 channels.
    const int ox  = tx0 + (tid & 31);
    const int oyb = ty0 + (tid >> 5);
    int   o00[4], o01[4], o10[4], o11[4], ooff[4];
    float w00[4], w01[4], w10[4], w11[4];
#pragma unroll
    for (int k = 0; k < 4; ++k) {
        const int oy = oyb + 8 * k;
        float ix, iy;
        srcxy((float)ox, (float)oy, ix, iy);
        const float x0f = floorf(ix), y0f = floorf(iy);
        const int x0 = (int)x0f, y0 = (int)y0f;
        const int x1 = x0 + 1,  y1 = y0 + 1;
        const float wx1 = ix - x0f, wx0 = 1.0f - wx1;
        const float wy1 = iy - y0f, wy0 = 1.0f - wy1;
        const float vx0 = (x0 >= 0 && x0 < W) ? 1.0f : 0.0f;
        const float vx1 = (x1 >= 0 && x1 < W) ? 1.0f : 0.0f;
        const float vy0 = (y0 >= 0 && y0 < H) ? 1.0f : 0.0f;
        const float vy1 = (y1 >= 0 && y1 < H) ? 1.0f : 0.0f;
        w00[k] = wy0 * wx0 * vy0 * vx0;
        w01[k] = wy0 * wx1 * vy0 * vx1;
        w10[k] = wy1 * wx0 * vy1 * vx0;
        w11[k] = wy1 * wx1 * vy1 * vx1;
        const int x0c = min(max(x0, 0), W - 1) - xlo;
        const int x1c = min(max(x1, 0), W - 1) - xlo;
        const int y0c = min(max(y0, 0), H - 1) - ylo;
        const int y1c = min(max(y1, 0), H - 1) - ylo;
        o00[k] = y0c * stride + x0c;
        o01[k] = y0c * stride + x1c;
        o10[k] = y1c * stride + x0c;
        o11[k] = y1c * stride + x1c;
        ooff[k] = oy * W + ox;
    }

    const size_t batoff = (size_t)b * C * HW;
    const float* iplane = img + batoff + (size_t)ylo * W + xlo;
    float*       oplane = out + batoff;
    const int lx = tid & 63, ry = tid >> 6;   // 64-lane coalesced row loads

    for (int ch = 0; ch < C; ++ch) {
        // Stage this channel's bbox into LDS (bw <= 48 < 64: one col iter).
        if (lx < bw) {
            for (int r = ry; r < bh; r += 4)
                lds[r * stride + lx] = iplane[(size_t)ch * HW + r * W + lx];
        }
        __syncthreads();
#pragma unroll
        for (int k = 0; k < 4; ++k) {
            float v = lds[o00[k]] * w00[k] + lds[o01[k]] * w01[k]
                    + lds[o10[k]] * w10[k] + lds[o11[k]] * w11[k];
            oplane[(size_t)ch * HW + ooff[k]] = v;
        }
        __syncthreads();
    }
}

extern "C" void kernel_launch(void* const* d_in, const int* in_sizes, int n_in,
                              void* d_out, int out_size, void* d_ws, size_t ws_size,
                              hipStream_t stream) {
    const float* img    = (const float*)d_in[0];
    const float* params = (const float*)d_in[1];
    float*       out    = (float*)d_out;

    constexpr int grid = B * (H / TILE) * (W / TILE);   // 16*256 = 4096 blocks
    grid_sampler_kernel<<<grid, 256, 0, stream>>>(img, params, out);
}

// Round 3
// 260.488 us; speedup vs baseline: 1.3689x; 1.0215x over previous
//
#include <hip/hip_runtime.h>
#include <math.h>

// img (16,8,512,512) fp32, params (16,3) fp32, out (16,8,512,512) fp32.
constexpr int B = 16, C = 8, H = 512, W = 512;
constexpr int HW = H * W;
constexpr int TILE = 32;          // 32x32 output tile per block
// Source bbox span of a rotated 32x32 tile <= 31*(|c|+|s|)+2 <= 46; +2 margin
// for the always-adjacent x-pair trick. bw_s <= 50, stride <= 51, bh <= 48.
// Slots needed <= bh*stride + stride + 1 <= 48*51+52 = 2500.
constexpr int MAXPOS = 2560;      // float2 slots -> 20 KiB -> 8 blocks/CU

__global__ __launch_bounds__(256) void grid_sampler_kernel(
    const float* __restrict__ img,
    const float* __restrict__ params,
    float* __restrict__ out) {
    __shared__ float2 lds2[MAXPOS];
    const int tid = threadIdx.x;
    const int blk = blockIdx.x;
    const int b   = blk >> 8;            // 256 tiles (16x16) per batch
    const int tt  = blk & 255;
    const int ty0 = (tt >> 4) * TILE;
    const int tx0 = (tt & 15) * TILE;

    // Wave-uniform per-batch params.
    const float tpx = params[b * 3 + 0] * (1.0f / W);
    const float tpy = params[b * 3 + 1] * (1.0f / H);
    const float th  = params[b * 3 + 2];
    const float c = cosf(th), s = sinf(th);

    // Identical expression sequence for bbox corners and per-pixel sampling
    // (monotone in x,y) so per-pixel floors stay inside corner-derived bbox;
    // we additionally carry a 1-texel margin on every side.
    auto srcxy = [&](float x, float y, float& ix, float& iy) {
        float xs = (2.0f * x + 1.0f) * (1.0f / W) - 1.0f;
        float ys = (2.0f * y + 1.0f) * (1.0f / H) - 1.0f;
        float gx = c * xs - s * ys + tpx;
        float gy = s * xs + c * ys + tpy;
        ix = ((gx + 1.0f) * (float)W - 1.0f) * 0.5f;
        iy = ((gy + 1.0f) * (float)H - 1.0f) * 0.5f;
    };

    float ixa, iya, ixb, iyb, ixc, iyc, ixd, iyd;
    srcxy((float)tx0,            (float)ty0,            ixa, iya);
    srcxy((float)(tx0 + TILE-1), (float)ty0,            ixb, iyb);
    srcxy((float)tx0,            (float)(ty0 + TILE-1), ixc, iyc);
    srcxy((float)(tx0 + TILE-1), (float)(ty0 + TILE-1), ixd, iyd);
    const float ixmin = fminf(fminf(ixa, ixb), fminf(ixc, ixd));
    const float ixmax = fmaxf(fmaxf(ixa, ixb), fmaxf(ixc, ixd));
    const float iymin = fminf(fminf(iya, iyb), fminf(iyc, iyd));
    const float iymax = fmaxf(fmaxf(iya, iyb), fmaxf(iyc, iyd));
    const int xlo = min(max((int)floorf(ixmin), 0), W - 1);
    const int xhi = min(max((int)floorf(ixmax) + 1, 0), W - 1);
    const int ylo = min(max((int)floorf(iymin), 0), H - 1);
    const int yhi = min(max((int)floorf(iymax) + 1, 0), H - 1);
    const int bw = xhi - xlo + 1;        // <= 48
    const int bh = yhi - ylo + 1;        // <= 48
    const int xlo_s = xlo - 1;           // 1-texel left margin (may be -1)
    const int stride = (bw + 2) | 1;     // odd stride <= 51, covers [xlo-1, xhi+1]

    // Per-thread outputs: ox fixed, 4 rows spaced by 8. Grid math, folded
    // weights, LDS tap bases computed ONCE; reused across all 4 ch-groups.
    const int ox  = tx0 + (tid & 31);
    const int oyb = ty0 + (tid >> 5);
    int   base0[4], base1[4], ooff[4];
    float w00[4], w01[4], w10[4], w11[4];
#pragma unroll
    for (int k = 0; k < 4; ++k) {
        const int oy = oyb + 8 * k;
        float ix, iy;
        srcxy((float)ox, (float)oy, ix, iy);
        const float x0f = floorf(ix), y0f = floorf(iy);
        const int x0 = (int)x0f, y0 = (int)y0f;
        const int x1 = x0 + 1,  y1 = y0 + 1;
        const float wx1 = ix - x0f, wx0 = 1.0f - wx1;
        const float wy1 = iy - y0f, wy0 = 1.0f - wy1;
        const float vx0 = (x0 >= 0 && x0 < W) ? 1.0f : 0.0f;
        const float vx1 = (x1 >= 0 && x1 < W) ? 1.0f : 0.0f;
        const float vy0 = (y0 >= 0 && y0 < H) ? 1.0f : 0.0f;
        const float vy1 = (y1 >= 0 && y1 < H) ? 1.0f : 0.0f;
        w00[k] = wy0 * wx0 * vy0 * vx0;
        w01[k] = wy0 * wx1 * vy0 * vx1;
        w10[k] = wy1 * wx0 * vy1 * vx0;
        w11[k] = wy1 * wx1 * vy1 * vx1;
        // x taps are always (xi, xi+1); clamped (0-weight) taps still land on
        // staged, finite cells. y rows clamped independently.
        const int xi  = min(max(x0 - xlo_s, 0), stride - 1);
        const int yi0 = min(max(y0 - ylo, 0), bh - 1);
        const int yi1 = min(max(y1 - ylo, 0), bh - 1);
        base0[k] = yi0 * stride + xi;
        base1[k] = yi1 * stride + xi;
        ooff[k]  = oy * W + ox;
    }

    const size_t batoff = (size_t)b * C * HW;
    const int lx = tid & 63, ry = tid >> 6;   // staging: 64-lane rows, 4 waves

    for (int g = 0; g < 4; ++g) {
        const float* p0 = img + batoff + (size_t)(2 * g) * HW + (size_t)ylo * W;
        const float* p1 = p0 + HW;
        // Stage cols [0, stride] (<=52 lanes) of rows [0,bh): both channels
        // interleaved as float2. Source col clamped to the image row so every
        // staged cell is finite; clamp-duplicates only feed 0-weight taps.
        if (lx <= stride) {
            const int col = min(max(xlo_s + lx, 0), W - 1);
            for (int r = ry; r < bh; r += 4)
                lds2[r * stride + lx] = make_float2(p0[r * W + col], p1[r * W + col]);
        }
        __syncthreads();
        float* o0 = out + batoff + (size_t)(2 * g) * HW;
        float* o1 = o0 + HW;
#pragma unroll
        for (int k = 0; k < 4; ++k) {
            const float2 t00 = lds2[base0[k]], t01 = lds2[base0[k] + 1];
            const float2 t10 = lds2[base1[k]], t11 = lds2[base1[k] + 1];
            const float vx = t00.x * w00[k] + t01.x * w01[k]
                           + t10.x * w10[k] + t11.x * w11[k];
            const float vy = t00.y * w00[k] + t01.y * w01[k]
                           + t10.y * w10[k] + t11.y * w11[k];
            o0[ooff[k]] = vx;
            o1[ooff[k]] = vy;
        }
        __syncthreads();
    }
}

extern "C" void kernel_launch(void* const* d_in, const int* in_sizes, int n_in,
                              void* d_out, int out_size, void* d_ws, size_t ws_size,
                              hipStream_t stream) {
    const float* img    = (const float*)d_in[0];
    const float* params = (const float*)d_in[1];
    float*       out    = (float*)d_out;

    constexpr int grid = B * (H / TILE) * (W / TILE);   // 4096 blocks
    grid_sampler_kernel<<<grid, 256, 0, stream>>>(img, params, out);
}

// Round 5
// 242.547 us; speedup vs baseline: 1.4701x; 1.0740x over previous
//
#include <hip/hip_runtime.h>
#include <math.h>

// img (16,8,512,512) fp32, params (16,3) fp32, out (16,8,512,512) fp32.
constexpr int B = 16, C = 8, H = 512, W = 512;
constexpr int HW = H * W;
constexpr int TILE = 32;           // 32x32 output tile per block
constexpr int ROWS = 48;           // staged source rows (bbox span <= 46)
constexpr int LSTR = 79;           // LDS row stride (floats): bank=(15y+x)&32-1
constexpr int BUFSZ = ROWS * LSTR; // 3792 floats = 14.8 KiB; x2 buffers

// Async global->LDS: per-lane global address, LDS dst = uniform base + lane*4.
__device__ __forceinline__ void dma4(const float* g, float* l) {
    __builtin_amdgcn_global_load_lds(
        (const __attribute__((address_space(1))) unsigned int*)g,
        (__attribute__((address_space(3))) unsigned int*)l,
        4, 0, 0);
}

__global__ __launch_bounds__(256) void grid_sampler_kernel(
    const float* __restrict__ img,
    const float* __restrict__ params,
    float* __restrict__ out) {
    __shared__ float lds[2][BUFSZ];
    const int tid = threadIdx.x;
    const int blk = blockIdx.x;
    const int b   = blk >> 8;            // 256 tiles (16x16) per batch
    const int tt  = blk & 255;
    const int ty0 = (tt >> 4) * TILE;
    const int tx0 = (tt & 15) * TILE;

    // Zero col 64 of every row in both buffers: the only un-staged LDS cell a
    // (zero-weight) tap can reach; must be finite, LDS starts uninitialized.
    if (tid < 96) {
        const int bb = tid / ROWS, r = tid % ROWS;
        lds[bb][r * LSTR + 64] = 0.0f;
    }

    // Wave-uniform per-batch params.
    const float tpx = params[b * 3 + 0] * (1.0f / W);
    const float tpy = params[b * 3 + 1] * (1.0f / H);
    const float th  = params[b * 3 + 2];
    const float c = cosf(th), s = sinf(th);

    // Identical fp expression for bbox corners and per-pixel sampling; gx/gy
    // monotone in x,y (per fixed other coord) so corner min bounds every pixel.
    auto srcxy = [&](float x, float y, float& ix, float& iy) {
        float xs = (2.0f * x + 1.0f) * (1.0f / W) - 1.0f;
        float ys = (2.0f * y + 1.0f) * (1.0f / H) - 1.0f;
        float gx = c * xs - s * ys + tpx;
        float gy = s * xs + c * ys + tpy;
        ix = ((gx + 1.0f) * (float)W - 1.0f) * 0.5f;
        iy = ((gy + 1.0f) * (float)H - 1.0f) * 0.5f;
    };

    float ixa, iya, ixb, iyb, ixc, iyc, ixd, iyd;
    srcxy((float)tx0,             (float)ty0,             ixa, iya);
    srcxy((float)(tx0 + TILE-1),  (float)ty0,             ixb, iyb);
    srcxy((float)tx0,             (float)(ty0 + TILE-1),  ixc, iyc);
    srcxy((float)(tx0 + TILE-1),  (float)(ty0 + TILE-1),  ixd, iyd);
    const float ixmin = fminf(fminf(ixa, ixb), fminf(ixc, ixd));
    const float iymin = fminf(fminf(iya, iyb), fminf(iyc, iyd));
    const int xlo = min(max((int)floorf(ixmin), 0), W - 1);
    const int ylo = min(max((int)floorf(iymin), 0), H - 1);
    // 1-texel left margin (R3 trick): LDS col ln holds image col
    // clamp(xls+ln, 0, W-1); duplication only ever feeds 0-weight taps.
    const int xls = xlo - 1;             // may be -1
    const int yls = min(ylo, H - ROWS);  // rows always in-image

    // Thread -> one output row, 4 consecutive cols (float4 store).
    const int oy  = ty0 + (tid >> 3);
    const int oxb = tx0 + (tid & 7) * 4;
    int   a0[4], a1[4];
    float w00[4], w01[4], w10[4], w11[4];
#pragma unroll
    for (int j = 0; j < 4; ++j) {
        float ix, iy;
        srcxy((float)(oxb + j), (float)oy, ix, iy);
        const float x0f = floorf(ix), y0f = floorf(iy);
        const int x0 = (int)x0f, y0 = (int)y0f;
        const int x1 = x0 + 1,  y1 = y0 + 1;
        const float wx1 = ix - x0f, wx0 = 1.0f - wx1;
        const float wy1 = iy - y0f, wy0 = 1.0f - wy1;
        const float vx0 = (x0 >= 0 && x0 < W) ? 1.0f : 0.0f;
        const float vx1 = (x1 >= 0 && x1 < W) ? 1.0f : 0.0f;
        const float vy0 = (y0 >= 0 && y0 < H) ? 1.0f : 0.0f;
        const float vy1 = (y1 >= 0 && y1 < H) ? 1.0f : 0.0f;
        w00[j] = wy0 * wx0 * vy0 * vx0;
        w01[j] = wy0 * wx1 * vy0 * vx1;
        w10[j] = wy1 * wx0 * vy1 * vx0;
        w11[j] = wy1 * wx1 * vy1 * vx1;
        // Valid x0 >= xlo -> xi = x0-xls in [1,48]; x0=-1 (0-wt) -> xi=0 and
        // the x1 tap reads LDS col 1 = image col 0 (correct). Far-OOB clamps
        // hit staged/zeroed finite cells with 0 weight.
        const int xi  = min(max(x0 - xls, 0), 63);
        const int yi0 = min(max(y0 - yls, 0), ROWS - 1);
        const int yi1 = min(max(y1 - yls, 0), ROWS - 1);
        a0[j] = yi0 * LSTR + xi;
        a1[j] = yi1 * LSTR + xi;
    }

    const size_t batoff = (size_t)b * C * HW;
    const int ooff = oy * W + oxb;
    const int wv = tid >> 6, ln = tid & 63;
    // Per-lane clamped source column; wave wv stages rows [12*wv, 12*wv+12).
    const int scol = min(max(xls + ln, 0), W - 1);
    const float* sbase = img + batoff + (size_t)yls * W + scol;

    // Prologue: async-stage channel 0 into buffer 0.
#pragma unroll
    for (int j2 = 0; j2 < 12; ++j2) {
        const int r = 12 * wv + j2;
        dma4(sbase + (size_t)r * W, &lds[0][r * LSTR]);
    }

#pragma unroll
    for (int g = 0; g < 8; ++g) {
        if (g < 7) {
            // Prefetch channel g+1 into the other buffer (12 DMAs/wave).
            const float* sp = sbase + (size_t)(g + 1) * HW;
            float* dp = &lds[(g + 1) & 1][0];
#pragma unroll
            for (int j2 = 0; j2 < 12; ++j2) {
                const int r = 12 * wv + j2;
                dma4(sp + (size_t)r * W, dp + r * LSTR);
            }
            // Wait only the OLDER DMAs (phase g); prefetch stays in flight.
            asm volatile("s_waitcnt vmcnt(12) lgkmcnt(0)\n\ts_barrier" ::: "memory");
        } else {
            asm volatile("s_waitcnt vmcnt(0) lgkmcnt(0)\n\ts_barrier" ::: "memory");
        }

        const float* bp = &lds[g & 1][0];
        float4 v;
#pragma unroll
        for (int j = 0; j < 4; ++j) {
            const float t00 = bp[a0[j]], t01 = bp[a0[j] + 1];
            const float t10 = bp[a1[j]], t11 = bp[a1[j] + 1];
            ((float*)&v)[j] = t00 * w00[j] + t01 * w01[j]
                            + t10 * w10[j] + t11 * w11[j];
        }
        *(float4*)(out + batoff + (size_t)g * HW + ooff) = v;

        if (g < 7)  // protect buf[g&1] before phase g+2's DMAs overwrite it
            asm volatile("s_waitcnt lgkmcnt(0)\n\ts_barrier" ::: "memory");
    }
}

extern "C" void kernel_launch(void* const* d_in, const int* in_sizes, int n_in,
                              void* d_out, int out_size, void* d_ws, size_t ws_size,
                              hipStream_t stream) {
    const float* img    = (const float*)d_in[0];
    const float* params = (const float*)d_in[1];
    float*       out    = (float*)d_out;

    constexpr int grid = B * (H / TILE) * (W / TILE);   // 4096 blocks
    grid_sampler_kernel<<<grid, 256, 0, stream>>>(img, params, out);
}